// Round 8
// baseline (611.766 us; speedup 1.0000x reference)
//
#include <hip/hip_runtime.h>
#include <hip/hip_bf16.h>

#define UF 512
#define EF 256
#define NB 64
#define NU 1024
#define NEN 1024

typedef __attribute__((ext_vector_type(8))) short short8;    // 8 bf16 (4 VGPRs)
typedef __attribute__((ext_vector_type(4))) float floatx4;   // MFMA acc / ext-vector f32x4
typedef __attribute__((ext_vector_type(2))) _Float16 half2v; // packed f16 pair (1 VGPR)
typedef __attribute__((ext_vector_type(4))) _Float16 half4v; // packed f16 quad (2 VGPRs, 8B)

typedef unsigned short ushort_t;

__device__ inline short2 cvt2(float a, float b) {
    __hip_bfloat162 h = __float22bfloat162_rn(make_float2(a, b));
    union { __hip_bfloat162 h; short2 s; } u;
    u.h = h;
    return u.s;
}

__device__ inline short8 cvt8v(floatx4 x, floatx4 y) {
    union { short8 v; short2 s[4]; } u;
    u.s[0] = cvt2(x[0], x[1]);
    u.s[1] = cvt2(x[2], x[3]);
    u.s[2] = cvt2(y[0], y[1]);
    u.s[3] = cvt2(y[2], y[3]);
    return u.v;
}

__device__ inline ushort_t f2bfbits(float f) {
    unsigned u = __float_as_uint(f);
    u += 0x7FFFu + ((u >> 16) & 1u);   // round-to-nearest-even
    return (ushort_t)(u >> 16);
}

// ---------------- K1: ||v||^2 ----------------
__global__ void knorm(const float* __restrict__ v, float* __restrict__ ws0) {
    int t = blockIdx.x * 256 + threadIdx.x;     // 65536 threads, float2 each
    float2 x = ((const float2*)v)[t];
    float s = x.x * x.x + x.y * x.y;
    #pragma unroll
    for (int m = 1; m < 64; m <<= 1) s += __shfl_xor(s, m);
    __shared__ float ls[4];
    int w = threadIdx.x >> 6;
    if ((threadIdx.x & 63) == 0) ls[w] = s;
    __syncthreads();
    if (threadIdx.x == 0) atomicAdd(ws0, ls[0] + ls[1] + ls[2] + ls[3]);
}

// ---------------- K2: W=g*v/||v|| -> bf16 ; efeat -> bf16 (skip masked rows) ----------------
__global__ void kconv(const float* __restrict__ v, const float* __restrict__ g,
                      const float* __restrict__ ef, const float* __restrict__ ws0,
                      const int* __restrict__ nen,
                      ushort_t* __restrict__ wsW, ushort_t* __restrict__ wsE) {
    int bid = blockIdx.x;
    if (bid < 128) {
        int t = bid * 256 + threadIdx.x;        // 32768 threads * 4 elems = 131072
        float s = g[0] * rsqrtf(ws0[0]);
        float4 x = ((const float4*)v)[t];
        short2 a = cvt2(x.x * s, x.y * s);
        short2 b = cvt2(x.z * s, x.w * s);
        ushort4 o;
        o.x = (ushort_t)a.x; o.y = (ushort_t)a.y; o.z = (ushort_t)b.x; o.w = (ushort_t)b.y;
        ((ushort4*)wsW)[t] = o;
    } else {
        long t = (long)(bid - 128) * 256 + threadIdx.x;  // float4 index into efeat
        int row = (int)(t >> 6);                 // 64 float4 per 256-col row
        int n = row & (NEN - 1);
        int b = row >> 10;
        if (n < nen[b]) {                        // rows >= ne are never read downstream
            // efeat is read exactly once: nontemporal, don't pollute L2.
            floatx4 x = __builtin_nontemporal_load((const floatx4*)ef + t);
            short2 a = cvt2(x[0], x[1]);
            short2 c = cvt2(x[2], x[3]);
            ushort4 o;
            o.x = (ushort_t)a.x; o.y = (ushort_t)a.y; o.z = (ushort_t)c.x; o.w = (ushort_t)c.y;
            ((ushort4*)wsE)[t] = o;
        }
    }
}

// ---------------- K3+K4 fused: proj GEMM -> LDS -> attention softmax ----------------
// Block = one (b, ut) pair; 2048 blocks, 4 waves.
// OCCUPANCY: __launch_bounds__(256,3) => ~170 unified regs/wave budget. Paid for
// by moving the t=1 exp-accumulator chain to LDS (accL, 136B row stride = 34
// words => ds b64 ops land 2-way bank aliasing = free). Phase-2 live set:
// af 32 + bf 32 + acc0 32 + psum/misc ~35 ≈ 130 regs. LDS 52.2KB => 3 blocks/CU
// = 12 waves/CU (was ~6.5).
// Phase 1: proj[32x256] GEMM; BOTH A (HBM) and W (L2) double-buffered one
//   k-step ahead. Epilogue -> padded Pl (264 cols: af b128 reads 2-way = free).
// Phase 2: balanced interleaved skip (wave w owns col0 = ns*64 + w*16),
//   cross-step E double-buffer prefetch, exp stored f16 (t=0 regs, t=1 LDS).
__launch_bounds__(256, 3)
__global__ void kfused(const float* __restrict__ A, const ushort_t* __restrict__ W,
                       const float* __restrict__ bias, const ushort_t* __restrict__ E,
                       const int* __restrict__ nen, float* __restrict__ out) {
    const int tid = threadIdx.x;
    const int w = tid >> 6, L = tid & 63;
    const int rA = L & 15, q = L >> 4;
    const int bid = blockIdx.x;
    const int b = bid >> 5;              // b-major: L2 locality on E
    const int ut = bid & 31;             // 0..31, 32 u-rows each
    const int ne = nen[b];

    __shared__ ushort_t Pl[32][264];     // proj tile, padded (16.9 KB)
    __shared__ ushort_t accL[256][68];   // t=1 exp chain: 16 ns x 4 halves, 136B stride (34.8 KB)
    __shared__ float lsum[4][32];

    // ---- Phase 1: GEMM ----
    {
        const long m0 = (long)b * NU + (long)ut * 32;
        floatx4 acc[2][4];
        #pragma unroll
        for (int m = 0; m < 2; m++)
            #pragma unroll
            for (int n = 0; n < 4; n++) acc[m][n] = (floatx4){0.f, 0.f, 0.f, 0.f};

        const float* a0 = A + (m0 + rA) * UF + q * 8;
        const float* a1 = A + (m0 + 16 + rA) * UF + q * 8;
        const ushort_t* wp[4];
        #pragma unroll
        for (int n = 0; n < 4; n++) wp[n] = W + (long)(w * 64 + n * 16 + rA) * UF + q * 8;

        // prime both pipelines (step 0)
        floatx4 x0 = *(const floatx4*)(a0);
        floatx4 y0 = *(const floatx4*)(a0 + 4);
        floatx4 x1 = *(const floatx4*)(a1);
        floatx4 y1 = *(const floatx4*)(a1 + 4);
        short8 wf[2][4];
        #pragma unroll
        for (int n = 0; n < 4; n++) wf[0][n] = *(const short8*)(wp[n]);

        #pragma unroll 2
        for (int s = 0; s < 16; s++) {
            const int cur = s & 1;               // compile-time under unroll-2
            const int ko = s * 32;
            short8 af0 = cvt8v(x0, y0);
            short8 af1 = cvt8v(x1, y1);
            if (s < 15) {                        // prefetch next step's A (HBM) + W (L2)
                x0 = *(const floatx4*)(a0 + ko + 32);
                y0 = *(const floatx4*)(a0 + ko + 36);
                x1 = *(const floatx4*)(a1 + ko + 32);
                y1 = *(const floatx4*)(a1 + ko + 36);
                #pragma unroll
                for (int n = 0; n < 4; n++) wf[cur ^ 1][n] = *(const short8*)(wp[n] + ko + 32);
            }
            #pragma unroll
            for (int n = 0; n < 4; n++) {
                acc[0][n] = __builtin_amdgcn_mfma_f32_16x16x32_bf16(af0, wf[cur][n], acc[0][n], 0, 0, 0);
                acc[1][n] = __builtin_amdgcn_mfma_f32_16x16x32_bf16(af1, wf[cur][n], acc[1][n], 0, 0, 0);
            }
        }

        #pragma unroll
        for (int n = 0; n < 4; n++) {
            const int col = w * 64 + n * 16 + rA;
            const float bv = bias[col];
            #pragma unroll
            for (int m = 0; m < 2; m++) {
                #pragma unroll
                for (int i = 0; i < 4; i++) {
                    float val = acc[m][n][i] + bv;
                    val = fmaxf(val, 0.f);
                    Pl[m * 16 + q * 4 + i][col] = f2bfbits(val);
                }
            }
        }
    }
    __syncthreads();

    // ---- Phase 2: attention ----
    // Preload A-frags from LDS (one-time); reused across all active n-steps.
    short8 af[2][8];
    #pragma unroll
    for (int t = 0; t < 2; t++)
        #pragma unroll
        for (int s = 0; s < 8; s++)
            af[t][s] = *(const short8*)&Pl[t * 16 + rA][s * 32 + q * 8];

    half2v acc0[16][2];                  // t=0 exp chain, f16-packed, in regs
    #pragma unroll
    for (int ns = 0; ns < 16; ns++) {
        acc0[ns][0] = (half2v){(_Float16)0.f, (_Float16)0.f};
        acc0[ns][1] = (half2v){(_Float16)0.f, (_Float16)0.f};
    }
    float psum[2][4];
    #pragma unroll
    for (int t = 0; t < 2; t++)
        #pragma unroll
        for (int i = 0; i < 4; i++) psum[t][i] = 0.f;

    // E rows for this wave's INTERLEAVED steps: row = ns*64 + w*16 + rA
    const ushort_t* erow = E + (long)(b * NEN + w * 16 + rA) * EF + q * 8;

    short8 bf[2][8];
    if (w * 16 < ne) {                   // prologue: load step 0
        #pragma unroll
        for (int s = 0; s < 8; s++) bf[0][s] = *(const short8*)(erow + s * 32);
    }

    #pragma unroll
    for (int ns = 0; ns < 16; ns++) {
        const int col0 = ns * 64 + w * 16;
        if (col0 < ne) {                 // wave-uniform skip, balanced across waves
            const int cur = ns & 1;      // compile-time under full unroll
            if (ns < 15) {               // prefetch step ns+1's E (garbage-safe)
                const ushort_t* epn = erow + (long)(ns + 1) * 64 * EF;
                #pragma unroll
                for (int s = 0; s < 8; s++) bf[cur ^ 1][s] = *(const short8*)(epn + s * 32);
            }
            floatx4 c0 = (floatx4){0.f, 0.f, 0.f, 0.f};
            floatx4 c1 = (floatx4){0.f, 0.f, 0.f, 0.f};
            #pragma unroll
            for (int s = 0; s < 8; s++) {
                c0 = __builtin_amdgcn_mfma_f32_16x16x32_bf16(af[0][s], bf[cur][s], c0, 0, 0, 0);
                c1 = __builtin_amdgcn_mfma_f32_16x16x32_bf16(af[1][s], bf[cur][s], c1, 0, 0, 0);
            }
            const int col = col0 + rA;
            const bool on = col < ne;    // boundary lanes: garbage E rows masked off
            #pragma unroll
            for (int i = 0; i < 4; i++) {
                float e0 = on ? __expf(c0[i] * 0.0625f) : 0.f;
                float e1 = on ? __expf(c1[i] * 0.0625f) : 0.f;
                psum[0][i] += e0; psum[1][i] += e1;
                c0[i] = e0; c1[i] = e1;
            }
            acc0[ns][0] = (half2v){(_Float16)c0[0], (_Float16)c0[1]};
            acc0[ns][1] = (half2v){(_Float16)c0[2], (_Float16)c0[3]};
            half4v h1 = {(_Float16)c1[0], (_Float16)c1[1], (_Float16)c1[2], (_Float16)c1[3]};
            *(half4v*)&accL[tid][ns * 4] = h1;   // 8B b64 write, 2-way = free
        }
    }

    // Row sums: reduce over the 16 lanes sharing q (cols), then across waves via LDS.
    #pragma unroll
    for (int t = 0; t < 2; t++)
        #pragma unroll
        for (int i = 0; i < 4; i++) {
            float s = psum[t][i];
            s += __shfl_xor(s, 1);
            s += __shfl_xor(s, 2);
            s += __shfl_xor(s, 4);
            s += __shfl_xor(s, 8);
            psum[t][i] = s;
        }
    if (rA == 0) {
        #pragma unroll
        for (int t = 0; t < 2; t++)
            #pragma unroll
            for (int i = 0; i < 4; i++)
                lsum[w][t * 16 + q * 4 + i] = psum[t][i];
    }
    __syncthreads();

    float inv[2][4];
    #pragma unroll
    for (int t = 0; t < 2; t++)
        #pragma unroll
        for (int i = 0; i < 4; i++) {
            const int r = t * 16 + q * 4 + i;
            const float tot = lsum[0][r] + lsum[1][r] + lsum[2][r] + lsum[3][r];
            inv[t][i] = (ne > 0) ? (1.f / tot) : 0.f;
        }

    const float uni = 1.f / 1024.f;
    // out is never re-read: nontemporal stores keep the 268MB stream out of L2.
    float* orow = out + ((long)(b * NU + ut * 32)) * (long)NEN + w * 16;
    #pragma unroll
    for (int ns = 0; ns < 16; ns++) {
        const bool act = (ns * 64 + w * 16) < ne;    // wave-uniform
        half4v h1 = {(_Float16)0.f, (_Float16)0.f, (_Float16)0.f, (_Float16)0.f};
        if (act) h1 = *(const half4v*)&accL[tid][ns * 4];
        #pragma unroll
        for (int i = 0; i < 4; i++) {
            const int u0 = q * 4 + i;                // t=0 rows
            const float n0 = (float)acc0[ns][i >> 1][i & 1];
            const float v0 = (ne == 0) ? uni : n0 * inv[0][i];
            __builtin_nontemporal_store(v0, &orow[(long)u0 * NEN + ns * 64 + rA]);
            const int u1 = 16 + q * 4 + i;           // t=1 rows
            const float n1 = (float)h1[i];
            const float v1 = (ne == 0) ? uni : n1 * inv[1][i];
            __builtin_nontemporal_store(v1, &orow[(long)u1 * NEN + ns * 64 + rA]);
        }
    }
}

extern "C" void kernel_launch(void* const* d_in, const int* in_sizes, int n_in,
                              void* d_out, int out_size, void* d_ws, size_t ws_size,
                              hipStream_t stream) {
    (void)in_sizes; (void)n_in; (void)out_size; (void)ws_size;
    const float* ufeat = (const float*)d_in[0];
    const float* efeat = (const float*)d_in[1];
    const int*   nen   = (const int*)d_in[2];
    const float* v     = (const float*)d_in[3];
    const float* g     = (const float*)d_in[4];
    const float* bias  = (const float*)d_in[5];
    float* out = (float*)d_out;

    float*    ws0 = (float*)d_ws;
    ushort_t* wsW = (ushort_t*)((char*)d_ws + 1024);        // 256 KB
    ushort_t* wsE = (ushort_t*)((char*)d_ws + (1u << 20));  // 32 MB

    hipMemsetAsync(d_ws, 0, 256, stream);
    knorm<<<256, 256, 0, stream>>>(v, ws0);
    kconv<<<16512, 256, 0, stream>>>(v, g, efeat, ws0, nen, wsW, wsE);
    kfused<<<2048, 256, 0, stream>>>(ufeat, wsW, bias, wsE, nen, out);
}

// Round 9
// 548.043 us; speedup vs baseline: 1.1163x; 1.1163x over previous
//
#include <hip/hip_runtime.h>
#include <hip/hip_bf16.h>

#define UF 512
#define EF 256
#define NB 64
#define NU 1024
#define NEN 1024

typedef __attribute__((ext_vector_type(8))) short short8;    // 8 bf16 (4 VGPRs)
typedef __attribute__((ext_vector_type(4))) float floatx4;   // MFMA acc / ext-vector f32x4
typedef __attribute__((ext_vector_type(2))) _Float16 half2v; // packed f16 pair (1 VGPR)

typedef unsigned short ushort_t;

__device__ inline short2 cvt2(float a, float b) {
    __hip_bfloat162 h = __float22bfloat162_rn(make_float2(a, b));
    union { __hip_bfloat162 h; short2 s; } u;
    u.h = h;
    return u.s;
}

__device__ inline short8 cvt8v(floatx4 x, floatx4 y) {
    union { short8 v; short2 s[4]; } u;
    u.s[0] = cvt2(x[0], x[1]);
    u.s[1] = cvt2(x[2], x[3]);
    u.s[2] = cvt2(y[0], y[1]);
    u.s[3] = cvt2(y[2], y[3]);
    return u.v;
}

__device__ inline ushort_t f2bfbits(float f) {
    unsigned u = __float_as_uint(f);
    u += 0x7FFFu + ((u >> 16) & 1u);   // round-to-nearest-even
    return (ushort_t)(u >> 16);
}

// ---------------- K1: ||v||^2 ----------------
__global__ void knorm(const float* __restrict__ v, float* __restrict__ ws0) {
    int t = blockIdx.x * 256 + threadIdx.x;     // 65536 threads, float2 each
    float2 x = ((const float2*)v)[t];
    float s = x.x * x.x + x.y * x.y;
    #pragma unroll
    for (int m = 1; m < 64; m <<= 1) s += __shfl_xor(s, m);
    __shared__ float ls[4];
    int w = threadIdx.x >> 6;
    if ((threadIdx.x & 63) == 0) ls[w] = s;
    __syncthreads();
    if (threadIdx.x == 0) atomicAdd(ws0, ls[0] + ls[1] + ls[2] + ls[3]);
}

// ---------------- K2: W=g*v/||v|| -> bf16 ; efeat -> bf16 (skip masked rows) ----------------
__global__ void kconv(const float* __restrict__ v, const float* __restrict__ g,
                      const float* __restrict__ ef, const float* __restrict__ ws0,
                      const int* __restrict__ nen,
                      ushort_t* __restrict__ wsW, ushort_t* __restrict__ wsE) {
    int bid = blockIdx.x;
    if (bid < 128) {
        int t = bid * 256 + threadIdx.x;        // 32768 threads * 4 elems = 131072
        float s = g[0] * rsqrtf(ws0[0]);
        float4 x = ((const float4*)v)[t];
        short2 a = cvt2(x.x * s, x.y * s);
        short2 b = cvt2(x.z * s, x.w * s);
        ushort4 o;
        o.x = (ushort_t)a.x; o.y = (ushort_t)a.y; o.z = (ushort_t)b.x; o.w = (ushort_t)b.y;
        ((ushort4*)wsW)[t] = o;
    } else {
        long t = (long)(bid - 128) * 256 + threadIdx.x;  // float4 index into efeat
        int row = (int)(t >> 6);                 // 64 float4 per 256-col row
        int n = row & (NEN - 1);
        int b = row >> 10;
        if (n < nen[b]) {                        // rows >= ne are never read downstream
            // efeat is read exactly once: nontemporal, don't pollute L2.
            floatx4 x = __builtin_nontemporal_load((const floatx4*)ef + t);
            short2 a = cvt2(x[0], x[1]);
            short2 c = cvt2(x[2], x[3]);
            ushort4 o;
            o.x = (ushort_t)a.x; o.y = (ushort_t)a.y; o.z = (ushort_t)c.x; o.w = (ushort_t)c.y;
            ((ushort4*)wsE)[t] = o;
        }
    }
}

// ---------------- K3+K4 fused: proj GEMM -> LDS -> attention softmax ----------------
// Block = one (b, ut) pair; 2048 blocks, 4 waves. Round-7 phase 1 + main loop.
// EPILOGUE (new): the old scattered epilogue stored 64B segments (16 lanes x 4B)
// at 4KB row stride, nontemporal => HBM saw partial lines; 318MB at ~1.3TB/s was
// the whole kernel time. Now: stage each 256-col chunk of the prob tile in LDS
// (Cl[32][260], stride 260 dwords == 4 mod 32: stage writes 2-way = free), then
// each wave drains 8 full rows with 64-lane float4 stores = 1KB contiguous per
// instruction (full HBM lines). Cl overlays dead Pl via union.
__launch_bounds__(256, 2)
__global__ void kfused(const float* __restrict__ A, const ushort_t* __restrict__ W,
                       const float* __restrict__ bias, const ushort_t* __restrict__ E,
                       const int* __restrict__ nen, float* __restrict__ out) {
    const int tid = threadIdx.x;
    const int w = tid >> 6, L = tid & 63;
    const int rA = L & 15, q = L >> 4;
    const int bid = blockIdx.x;
    const int b = bid >> 5;              // b-major: L2 locality on E
    const int ut = bid & 31;             // 0..31, 32 u-rows each
    const int ne = nen[b];

    __shared__ union ShMem {
        ushort_t Pl[32][264];            // proj tile (phase 1 -> af preload), 16.9 KB
        float    Cl[32][260];            // epilogue chunk staging, 33.3 KB
    } sh;
    __shared__ float lsum[4][32];

    // ---- Phase 1: GEMM ----
    {
        const long m0 = (long)b * NU + (long)ut * 32;
        floatx4 acc[2][4];
        #pragma unroll
        for (int m = 0; m < 2; m++)
            #pragma unroll
            for (int n = 0; n < 4; n++) acc[m][n] = (floatx4){0.f, 0.f, 0.f, 0.f};

        const float* a0 = A + (m0 + rA) * UF + q * 8;
        const float* a1 = A + (m0 + 16 + rA) * UF + q * 8;
        const ushort_t* wp[4];
        #pragma unroll
        for (int n = 0; n < 4; n++) wp[n] = W + (long)(w * 64 + n * 16 + rA) * UF + q * 8;

        // prime the A pipeline (step 0)
        floatx4 x0 = *(const floatx4*)(a0);
        floatx4 y0 = *(const floatx4*)(a0 + 4);
        floatx4 x1 = *(const floatx4*)(a1);
        floatx4 y1 = *(const floatx4*)(a1 + 4);

        #pragma unroll 2
        for (int s = 0; s < 16; s++) {
            const int ko = s * 32;
            short8 wf[4];
            #pragma unroll
            for (int n = 0; n < 4; n++) wf[n] = *(const short8*)(wp[n] + ko);
            short8 af0 = cvt8v(x0, y0);
            short8 af1 = cvt8v(x1, y1);
            if (s < 15) {                        // prefetch next step's A (HBM)
                x0 = *(const floatx4*)(a0 + ko + 32);
                y0 = *(const floatx4*)(a0 + ko + 36);
                x1 = *(const floatx4*)(a1 + ko + 32);
                y1 = *(const floatx4*)(a1 + ko + 36);
            }
            #pragma unroll
            for (int n = 0; n < 4; n++) {
                acc[0][n] = __builtin_amdgcn_mfma_f32_16x16x32_bf16(af0, wf[n], acc[0][n], 0, 0, 0);
                acc[1][n] = __builtin_amdgcn_mfma_f32_16x16x32_bf16(af1, wf[n], acc[1][n], 0, 0, 0);
            }
        }

        #pragma unroll
        for (int n = 0; n < 4; n++) {
            const int col = w * 64 + n * 16 + rA;
            const float bv = bias[col];
            #pragma unroll
            for (int m = 0; m < 2; m++) {
                #pragma unroll
                for (int i = 0; i < 4; i++) {
                    float val = acc[m][n][i] + bv;
                    val = fmaxf(val, 0.f);
                    sh.Pl[m * 16 + q * 4 + i][col] = f2bfbits(val);
                }
            }
        }
    }
    __syncthreads();

    // ---- Phase 2: attention ----
    // Preload A-frags from LDS (one-time); reused across all active n-steps.
    short8 af[2][8];
    #pragma unroll
    for (int t = 0; t < 2; t++)
        #pragma unroll
        for (int s = 0; s < 8; s++)
            af[t][s] = *(const short8*)&sh.Pl[t * 16 + rA][s * 32 + q * 8];

    half2v acc[2][16][2];                // exp values, f16-packed (RTNE)
    #pragma unroll
    for (int t = 0; t < 2; t++)
        #pragma unroll
        for (int ns = 0; ns < 16; ns++) {
            acc[t][ns][0] = (half2v){(_Float16)0.f, (_Float16)0.f};
            acc[t][ns][1] = (half2v){(_Float16)0.f, (_Float16)0.f};
        }
    float psum[2][4];
    #pragma unroll
    for (int t = 0; t < 2; t++)
        #pragma unroll
        for (int i = 0; i < 4; i++) psum[t][i] = 0.f;

    // E rows for this wave's INTERLEAVED steps: row = ns*64 + w*16 + rA
    const ushort_t* erow = E + (long)(b * NEN + w * 16 + rA) * EF + q * 8;

    short8 bf[2][8];
    if (w * 16 < ne) {                   // prologue: load step 0
        #pragma unroll
        for (int s = 0; s < 8; s++) bf[0][s] = *(const short8*)(erow + s * 32);
    }

    #pragma unroll
    for (int ns = 0; ns < 16; ns++) {
        const int col0 = ns * 64 + w * 16;
        if (col0 < ne) {                 // wave-uniform skip, balanced across waves
            const int cur = ns & 1;      // compile-time under full unroll
            if (ns < 15) {               // prefetch step ns+1's E (garbage-safe)
                const ushort_t* epn = erow + (long)(ns + 1) * 64 * EF;
                #pragma unroll
                for (int s = 0; s < 8; s++) bf[cur ^ 1][s] = *(const short8*)(epn + s * 32);
            }
            floatx4 c0 = (floatx4){0.f, 0.f, 0.f, 0.f};
            floatx4 c1 = (floatx4){0.f, 0.f, 0.f, 0.f};
            #pragma unroll
            for (int s = 0; s < 8; s++) {
                c0 = __builtin_amdgcn_mfma_f32_16x16x32_bf16(af[0][s], bf[cur][s], c0, 0, 0, 0);
                c1 = __builtin_amdgcn_mfma_f32_16x16x32_bf16(af[1][s], bf[cur][s], c1, 0, 0, 0);
            }
            const int col = col0 + rA;
            const bool on = col < ne;    // boundary lanes: garbage E rows masked off
            #pragma unroll
            for (int i = 0; i < 4; i++) {
                float e0 = on ? __expf(c0[i] * 0.0625f) : 0.f;
                float e1 = on ? __expf(c1[i] * 0.0625f) : 0.f;
                psum[0][i] += e0; psum[1][i] += e1;
                c0[i] = e0; c1[i] = e1;
            }
            acc[0][ns][0] = (half2v){(_Float16)c0[0], (_Float16)c0[1]};
            acc[0][ns][1] = (half2v){(_Float16)c0[2], (_Float16)c0[3]};
            acc[1][ns][0] = (half2v){(_Float16)c1[0], (_Float16)c1[1]};
            acc[1][ns][1] = (half2v){(_Float16)c1[2], (_Float16)c1[3]};
        }
    }

    // Row sums: reduce over the 16 lanes sharing q (cols), then across waves via LDS.
    #pragma unroll
    for (int t = 0; t < 2; t++)
        #pragma unroll
        for (int i = 0; i < 4; i++) {
            float s = psum[t][i];
            s += __shfl_xor(s, 1);
            s += __shfl_xor(s, 2);
            s += __shfl_xor(s, 4);
            s += __shfl_xor(s, 8);
            psum[t][i] = s;
        }
    if (rA == 0) {
        #pragma unroll
        for (int t = 0; t < 2; t++)
            #pragma unroll
            for (int i = 0; i < 4; i++)
                lsum[w][t * 16 + q * 4 + i] = psum[t][i];
    }
    __syncthreads();

    float inv[2][4];
    #pragma unroll
    for (int t = 0; t < 2; t++)
        #pragma unroll
        for (int i = 0; i < 4; i++) {
            const int r = t * 16 + q * 4 + i;
            const float tot = lsum[0][r] + lsum[1][r] + lsum[2][r] + lsum[3][r];
            inv[t][i] = (ne > 0) ? (1.f / tot) : 0.f;
        }

    // ---- Coalesced epilogue: 4 chunks of 256 cols ----
    const float uni = 1.f / 1024.f;
    const long obase = ((long)(b * NU + ut * 32)) * (long)NEN;
    #pragma unroll
    for (int g = 0; g < 4; g++) {
        if (g > 0) __syncthreads();      // prior chunk's drain done before overwrite
        // stage: each lane writes its 32 final values for this chunk (2-way = free)
        #pragma unroll
        for (int ns2 = 0; ns2 < 4; ns2++) {
            const int ns = g * 4 + ns2;
            #pragma unroll
            for (int t = 0; t < 2; t++) {
                #pragma unroll
                for (int i = 0; i < 4; i++) {
                    const float num = (float)acc[t][ns][i >> 1][i & 1];
                    const float val = (ne == 0) ? uni : num * inv[t][i];
                    sh.Cl[t * 16 + q * 4 + i][ns2 * 64 + w * 16 + rA] = val;
                }
            }
        }
        __syncthreads();
        // drain: wave w writes rows w*8..w*8+7; 64 lanes x float4 = 1KB/instr
        #pragma unroll
        for (int j = 0; j < 8; j++) {
            const int r = w * 8 + j;
            floatx4 vv = *(const floatx4*)&sh.Cl[r][L * 4];
            __builtin_nontemporal_store(vv,
                (floatx4*)(out + obase + (long)r * NEN + g * 256 + L * 4));
        }
    }
}

extern "C" void kernel_launch(void* const* d_in, const int* in_sizes, int n_in,
                              void* d_out, int out_size, void* d_ws, size_t ws_size,
                              hipStream_t stream) {
    (void)in_sizes; (void)n_in; (void)out_size; (void)ws_size;
    const float* ufeat = (const float*)d_in[0];
    const float* efeat = (const float*)d_in[1];
    const int*   nen   = (const int*)d_in[2];
    const float* v     = (const float*)d_in[3];
    const float* g     = (const float*)d_in[4];
    const float* bias  = (const float*)d_in[5];
    float* out = (float*)d_out;

    float*    ws0 = (float*)d_ws;
    ushort_t* wsW = (ushort_t*)((char*)d_ws + 1024);        // 256 KB
    ushort_t* wsE = (ushort_t*)((char*)d_ws + (1u << 20));  // 32 MB

    hipMemsetAsync(d_ws, 0, 256, stream);
    knorm<<<256, 256, 0, stream>>>(v, ws0);
    kconv<<<16512, 256, 0, stream>>>(v, g, efeat, ws0, nen, wsW, wsE);
    kfused<<<2048, 256, 0, stream>>>(ufeat, wsW, bias, wsE, nen, out);
}